// Round 11
// baseline (257.417 us; speedup 1.0000x reference)
//
#include <hip/hip_runtime.h>
#include <hip/hip_cooperative_groups.h>

// SNN 2048->2048->2048->512, T=100, batch 32, LIF.
// R20 = R17 mega-kernel (proven 245.7us) + WIDEN every narrow phase
// (R19's cons/prestage reverted as neutral-negative):
//  - scan: 128 blk x 512 thr -> 256 blk x 256 active thr (2x CU coverage;
//    one feature-octet per block, 512B/t contiguous), unroll 4 -> 10
//    (10 loads in flight per dependent chain). scan2: 32 -> 64 blocks.
//  - encode: 200 blk x 16 m -> 400 blk x 8 m (39% -> 78% CU coverage).
//  - convw: 16 -> 32 rows/block (64 blocks per 2048-row weight).
//  - G2: MSPLIT=4 -> 512 blocks (was 256), <=1 tile/wave.
//  - G0/G1 gemm bit-identical (NCHUNK=8, MSPLIT=2 generic partition).
//
// Unified "octet-blocked" layout (pitch MTOT) for spikes AND I:
//   half_idx(v, m) = ((v>>3)*MTOT + m)*8 + (v&7)
// ws regions: R0 0 | R1 13107200 | I 26214400
// Phases: E{enc->R0 [0,400), cw0->R1 [400,464)} | G0(R1,R0->I) 512 |
//   S0{scan->R1 [0,256), cw1->R0 [256,320)} | G1(R0,R1->I) 512 |
//   S1{scan->R0 [0,256), cw2->R1 [256,272)} | G2(R1,R0->I) 512 | S2 [0,64)
#define T_STEPS 100
#define MTOT    3200
#define R0_OFF  0
#define R1_OFF  13107200
#define I_OFF   26214400

typedef _Float16 half8_t __attribute__((ext_vector_type(8)));
typedef _Float16 half4_t __attribute__((ext_vector_type(4)));
typedef float    f32x4   __attribute__((ext_vector_type(4)));

// ============ encode, 512-thr, 8 m/block, 32KB XOR-swizzled LDS =========
// koct = tid&255, mlh = tid>>8. Write conflict-free; read 2-way (free).
__device__ __forceinline__ void encode8_body(
    int blk, const float* __restrict__ x, const float* __restrict__ noise,
    _Float16* __restrict__ spk0, float* __restrict__ out, _Float16* smem)
{
    if (blk == 0 && threadIdx.x == 0) out[16384] = 0.0f;  // runs first
    const int tid  = threadIdx.x;
    const int m0   = blk * 8;
    const int koct = tid & 255;
    const int mlh  = tid >> 8;
    half8_t* lds = (half8_t*)smem;       // [8][256]
    #pragma unroll
    for (int mlq = 0; mlq < 4; ++mlq) {
        const int ml = mlq * 2 + mlh;
        const int m  = m0 + ml;
        const int t = m >> 5, b = m & 31;
        const float4 x1 = *(const float4*)(x + b * 2048 + koct * 8);
        const float4 x2 = *(const float4*)(x + b * 2048 + koct * 8 + 4);
        const float4 n1 = *(const float4*)(noise + (size_t)t * 65536 + b * 2048 + koct * 8);
        const float4 n2 = *(const float4*)(noise + (size_t)t * 65536 + b * 2048 + koct * 8 + 4);
        const float xr[8] = {x1.x,x1.y,x1.z,x1.w,x2.x,x2.y,x2.z,x2.w};
        const float nz[8] = {n1.x,n1.y,n1.z,n1.w,n2.x,n2.y,n2.z,n2.w};
        half8_t sp;
        #pragma unroll
        for (int q = 0; q < 8; ++q) {
            const float r = fminf(fmaxf(xr[q], 0.0f), 1.0f);
            sp[q] = (nz[q] < r) ? (_Float16)1.0f : (_Float16)0.0f;
        }
        lds[ml * 256 + (koct ^ ml)] = sp;
    }
    __syncthreads();
    #pragma unroll
    for (int r = 0; r < 4; ++r) {        // lanes: ml fast -> 128B contiguous
        const int ml  = tid & 7;
        const int oct = r * 64 + (tid >> 3);
        *(half8_t*)(spk0 + ((size_t)oct * MTOT + m0 + ml) * 8)
            = lds[ml * 256 + (oct ^ ml)];
    }
    __syncthreads();                     // smem dead before phase reuse
}

// ============ convw, 512-thr, 32 rows/block =============================
// Wf[(row>>4)*32768 + ((koct>>2)*64 + (koct&3)*16 + (row&15))*8 + j]
__device__ __forceinline__ void convw32_body(
    int cblk, const float* __restrict__ W, _Float16* __restrict__ Wf)
{
    const int koct = threadIdx.x & 255;
    const int rh   = threadIdx.x >> 8;   // 0..1
    #pragma unroll
    for (int r = 0; r < 16; ++r) {
        const int row = cblk * 32 + rh * 16 + r;
        const float* wp = W + (size_t)row * 2048 + koct * 8;
        const float4 f1 = *(const float4*)(wp);
        const float4 f2 = *(const float4*)(wp + 4);
        half8_t h = {(_Float16)f1.x,(_Float16)f1.y,(_Float16)f1.z,(_Float16)f1.w,
                     (_Float16)f2.x,(_Float16)f2.y,(_Float16)f2.z,(_Float16)f2.w};
        const size_t idx = (size_t)(row >> 4) * 32768
                         + ((size_t)((koct >> 2) * 64 + (koct & 3) * 16 + (row & 15))) * 8;
        *(half8_t*)(Wf + idx) = h;
    }
}

// ============ scan: 256 active thr/block, one octet/block ===============
// gid = blk*256 + tid (tid<256): j=gid&7, b=(gid>>3)&31, oct=gid>>8==blk.
// Per t the block touches 512B contiguous. Inactive waves (tid>=256)
// join only the reduction with c=0. One atomic per block (G12).
__device__ __forceinline__ void scan256_body(
    int blk, const _Float16* __restrict__ I, const float* __restrict__ bias,
    _Float16* __restrict__ spk_out, float* __restrict__ out,
    const int is_last, float* rsum)
{
    float cnt = 0.f;
    if (threadIdx.x < 256) {
        const int gid = blk * 256 + threadIdx.x;
        const int j   = gid & 7;
        const int b   = (gid >> 3) & 31;
        const int oct = gid >> 8;
        const int n   = oct * 8 + j;
        const float bi = bias[n];
        const size_t nbase = (size_t)oct * (MTOT * 8) + j;
        float mem = 0.f, syn = 0.f, osum = 0.f;
        #pragma unroll 10
        for (int t = 0; t < T_STEPS; ++t) {
            const int m = t * 32 + b;
            const float Iv = (float)I[nbase + (size_t)m * 8] + bi;
            syn = syn + (-syn / 5.0f + Iv);
            mem = mem + (-mem / 20.0f + syn);
            const float sv = (mem >= 1.0f) ? 1.0f : 0.0f;
            mem = (sv != 0.0f) ? 0.0f : mem;       // reset
            mem = (mem > 0.0f) ? mem : 0.0f;       // clamp negatives
            cnt += sv; osum += sv;
            if (!is_last) spk_out[nbase + (size_t)m * 8] = (_Float16)sv;
        }
        if (is_last) out[b * 512 + n] = osum * 0.01f;    // mean over T
    }
    // wave reduce -> LDS -> one atomic per block
    float c = cnt;
    #pragma unroll
    for (int s2 = 1; s2 < 64; s2 <<= 1) c += __shfl_xor(c, s2);
    const int wid = threadIdx.x >> 6;
    if ((threadIdx.x & 63) == 0) rsum[wid] = c;
    __syncthreads();
    if (threadIdx.x == 0) {
        float s = rsum[0];
        #pragma unroll
        for (int ww = 1; ww < 8; ++ww) s += rsum[ww];
        atomicAdd(&out[16384], s);
    }
    __syncthreads();   // rsum dead before smem reuse
}

// ============ 64-row GEMM body (R17 structure, generic MSPLIT) ==========
__device__ __forceinline__ half8_t ldB(const _Float16* __restrict__ p, int kq) {
    return *(const half8_t*)(p + (size_t)kq * (MTOT * 8));
}

__device__ __forceinline__ void stage_q(
    const _Float16* __restrict__ Wf, _Float16* __restrict__ wlds,
    const int nbb, const int q, const int w, const int lane)
{
    #pragma unroll
    for (int r = 0; r < 8; ++r) {
        const int unit = r * 512 + w * 64 + lane;        // 0..4095 (16B)
        const int s = unit >> 10, off = unit & 1023;
        const _Float16* src = Wf + (size_t)(4 * nbb + s) * 32768
                            + (size_t)q * 8192 + (size_t)off * 8;
        _Float16* dst = wlds + (size_t)unit * 8;
        __builtin_amdgcn_global_load_lds(
            (const __attribute__((address_space(1))) void*)src,
            (__attribute__((address_space(3))) void*)dst, 16, 0, 0);
    }
}

// One k-step: 4 A ds_reads feed 4|8 MFMAs; reload used B set <- kb+4.
template<bool HAS2>
__device__ __forceinline__ void kstep512(
    const _Float16* __restrict__ wlds, const _Float16* const (&bp)[2],
    half8_t (&bb)[2], f32x4 (&acc)[2][4],
    const int lane, const int quad, const int kb, const int j)
{
    half8_t a[4];
    #pragma unroll
    for (int s = 0; s < 4; ++s)
        a[s] = *(const half8_t*)(wlds + (size_t)s * 8192 + (size_t)(j * 64 + lane) * 8);
    #pragma unroll
    for (int s = 0; s < 4; ++s) {
        acc[0][s] = __builtin_amdgcn_mfma_f32_16x16x32_f16(a[s], bb[0], acc[0][s], 0, 0, 0);
        if (HAS2)
            acc[1][s] = __builtin_amdgcn_mfma_f32_16x16x32_f16(a[s], bb[1], acc[1][s], 0, 0, 0);
    }
    if (kb + 4 < 64) {                 // depth-4: reload for kb+4
        const int kq = (kb + 4) * 4 + quad;
        bb[0] = ldB(bp[0], kq);
        if (HAS2) bb[1] = ldB(bp[1], kq);
    }
}

template<bool HAS2>
__device__ __forceinline__ void gemm64s_run(
    const _Float16* __restrict__ Wf, const _Float16* __restrict__ spk,
    _Float16* __restrict__ I, _Float16* __restrict__ wlds,
    const int (&mt)[2], const int nbb, const int row_base,
    const int w, const int lane, const int quad, const int mi,
    const bool st)
{
    const _Float16* bp[2];
    bp[0] = spk + ((size_t)mt[0] * 16 + mi) * 8;
    bp[1] = spk + ((size_t)mt[1] * 16 + mi) * 8;

    // depth-4 B preload kb=0..3 FIRST (oldest in vmcnt order): the stage
    // drain at the first __syncthreads completes them for free.
    half8_t B0[2], B1[2], B2[2], B3[2];
    B0[0] = ldB(bp[0],      quad);
    B1[0] = ldB(bp[0],  4 + quad);
    B2[0] = ldB(bp[0],  8 + quad);
    B3[0] = ldB(bp[0], 12 + quad);
    if (HAS2) {
        B0[1] = ldB(bp[1],      quad);
        B1[1] = ldB(bp[1],  4 + quad);
        B2[1] = ldB(bp[1],  8 + quad);
        B3[1] = ldB(bp[1], 12 + quad);
    }

    stage_q(Wf, wlds, nbb, 0, w, lane);
    __syncthreads();

    f32x4 acc[2][4];
    #pragma unroll
    for (int u = 0; u < 2; ++u) {
        #pragma unroll
        for (int s = 0; s < 4; ++s) acc[u][s] = (f32x4){0, 0, 0, 0};
    }

    #pragma unroll 1
    for (int q = 0; q < 4; ++q) {
        #pragma unroll
        for (int j = 0; j < 16; j += 4) {
            kstep512<HAS2>(wlds, bp, B0, acc, lane, quad, q * 16 + j,     j);
            kstep512<HAS2>(wlds, bp, B1, acc, lane, quad, q * 16 + j + 1, j + 1);
            kstep512<HAS2>(wlds, bp, B2, acc, lane, quad, q * 16 + j + 2, j + 2);
            kstep512<HAS2>(wlds, bp, B3, acc, lane, quad, q * 16 + j + 3, j + 3);
        }
        __syncthreads();
        if (q < 3) {
            stage_q(Wf, wlds, nbb, q + 1, w, lane);
            __syncthreads();
        }
    }

    #pragma unroll
    for (int s = 0; s < 4; ++s) {
        const int n0 = row_base + s * 16 + quad * 4;
        const size_t obase = (size_t)(n0 >> 3) * (MTOT * 8) + (n0 & 7);
        #pragma unroll
        for (int u = 0; u < 2; ++u) {
            if (u == 0 && !st) continue;
            if (u == 1 && !HAS2) continue;
            half4_t h;
            #pragma unroll
            for (int r = 0; r < 4; ++r) h[r] = (_Float16)acc[u][s][r];
            *(half4_t*)(I + obase + (size_t)(mt[u] * 16 + mi) * 8) = h;
        }
    }
}

// Generic m-split: msl = (bid/NCHUNK)%MSPLIT owns jt-range
// [(jt*msl)/MSPLIT, (jt*(msl+1))/MSPLIT). MSPLIT=2 == R17's split.
template<int NCHUNK, int MSPLIT>
__device__ __forceinline__ void gemm64s_body(
    const int bid, const _Float16* __restrict__ Wf,
    const _Float16* __restrict__ spk, _Float16* __restrict__ I,
    _Float16* __restrict__ wlds)
{
    const int tid  = threadIdx.x;
    const int lane = tid & 63;
    const int w    = tid >> 6;            // wave 0..7
    const int mi   = lane & 15;
    const int quad = lane >> 4;
    const int chunk = bid % NCHUNK;
    const int rest  = bid / NCHUNK;
    const int msl   = rest % MSPLIT;
    const int nbb   = rest / MSPLIT;
    const int row_base = nbb * 64;
    const int jt     = (200 - chunk + NCHUNK - 1) / NCHUNK;
    const int jbase  = (jt * msl) / MSPLIT;
    const int jcount = (jt * (msl + 1)) / MSPLIT - jbase;
    const int rem    = jcount - 8;
    const bool has2  = (w < rem);
    const int r2     = rem > 0 ? rem : 0;
    const bool st    = has2 || (w + r2) < jcount;
    int jl_start = jbase + (has2 ? 2 * w : w + r2);
    const int jmax = jbase + jcount - 1;
    if (jl_start > jmax) jl_start = jmax;

    int mt[2];
    #pragma unroll
    for (int u = 0; u < 2; ++u) {
        int jl = jl_start + u;
        if (jl > jmax) jl = jmax;
        mt[u] = chunk + NCHUNK * jl;
    }

    if (has2) gemm64s_run<true >(Wf, spk, I, wlds, mt, nbb, row_base, w, lane, quad, mi, true);
    else      gemm64s_run<false>(Wf, spk, I, wlds, mt, nbb, row_base, w, lane, quad, mi, st);
}

// ==================== THE MEGA KERNEL (cooperative) =====================
__global__ __launch_bounds__(512, 4) void snn_mega_kernel(
    const float* __restrict__ x, const float* __restrict__ noise,
    const float* __restrict__ W0, const float* __restrict__ b0,
    const float* __restrict__ W1, const float* __restrict__ b1,
    const float* __restrict__ W2, const float* __restrict__ b2,
    _Float16* __restrict__ R0, _Float16* __restrict__ R1,
    _Float16* __restrict__ Ib, float* __restrict__ out)
{
    cooperative_groups::grid_group grid = cooperative_groups::this_grid();
    __shared__ _Float16 smem[32768];          // 64 KB, reused each phase
    const int blk = blockIdx.x;               // 0..511

    // E: encode -> R0 (400 blks x 8 m) ; convW0 -> R1 (64 blks x 32 rows)
    if (blk < 400)      encode8_body(blk, x, noise, R0, out, smem);
    else if (blk < 464) convw32_body(blk - 400, W0, R1);
    grid.sync();
    // G0: gemm0(R1, R0 -> I), all 512 blocks
    gemm64s_body<8, 2>(blk, R1, R0, Ib, smem);
    grid.sync();
    // S0: scan0 I->R1 (256 blks) ; convW1 -> R0 (64 blks)
    if (blk < 256)      scan256_body(blk, Ib, b0, R1, out, 0, (float*)smem);
    else if (blk < 320) convw32_body(blk - 256, W1, R0);
    grid.sync();
    // G1: gemm1(R0, R1 -> I), all 512 blocks
    gemm64s_body<8, 2>(blk, R0, R1, Ib, smem);
    grid.sync();
    // S1: scan1 I->R0 (256 blks) ; convW2 -> R1 (16 blks)
    if (blk < 256)      scan256_body(blk, Ib, b1, R0, out, 0, (float*)smem);
    else if (blk < 272) convw32_body(blk - 256, W2, R1);
    grid.sync();
    // G2: gemm2(R1, R0 -> I), all 512 blocks (MSPLIT=4)
    gemm64s_body<16, 4>(blk, R1, R0, Ib, smem);
    grid.sync();
    // S2: scan2 -> out (64 blks)
    if (blk < 64) scan256_body(blk, Ib, b2, nullptr, out, 1, (float*)smem);
}

// =================== legacy kernels (fallback path) =====================
__global__ __launch_bounds__(512, 4) void snn_enc512_kernel(
    const float* __restrict__ x, const float* __restrict__ noise,
    _Float16* __restrict__ spk0, float* __restrict__ out,
    const float* __restrict__ W, _Float16* __restrict__ Wf)
{
    __shared__ _Float16 smem[32768];
    if (blockIdx.x < 400) encode8_body(blockIdx.x, x, noise, spk0, out, smem);
    else                  convw32_body(blockIdx.x - 400, W, Wf);
}

__global__ __launch_bounds__(512, 4) void snn_scan_convw512_kernel(
    const _Float16* __restrict__ I, const float* __restrict__ bias,
    _Float16* __restrict__ spk_out, float* __restrict__ out,
    const int scan_blocks, const float* __restrict__ W,
    _Float16* __restrict__ Wf)
{
    __shared__ float rsum[8];
    if ((int)blockIdx.x < scan_blocks)
        scan256_body(blockIdx.x, I, bias, spk_out, out, 0, rsum);
    else
        convw32_body(blockIdx.x - scan_blocks, W, Wf);
}

__global__ __launch_bounds__(512, 4) void snn_scan512_kernel(
    const _Float16* __restrict__ I, const float* __restrict__ bias,
    float* __restrict__ out)
{
    __shared__ float rsum[8];
    scan256_body(blockIdx.x, I, bias, nullptr, out, 1, rsum);
}

template<int NCHUNK, int MSPLIT>
__global__ __launch_bounds__(512, 4) void snn_gemm64s_kernel(
    const _Float16* __restrict__ Wf, const _Float16* __restrict__ spk,
    _Float16* __restrict__ I)
{
    __shared__ _Float16 wlds[32768];
    gemm64s_body<NCHUNK, MSPLIT>(blockIdx.x, Wf, spk, I, wlds);
}

extern "C" void kernel_launch(void* const* d_in, const int* in_sizes, int n_in,
                              void* d_out, int out_size, void* d_ws, size_t ws_size,
                              hipStream_t stream) {
    // setup_inputs() dict order: x, noise, time_steps, W0, b0, W1, b1, W2, b2
    const float* x     = (const float*)d_in[0];
    const float* noise = (const float*)d_in[1];
    const float* W0 = (const float*)d_in[3];
    const float* b0 = (const float*)d_in[4];
    const float* W1 = (const float*)d_in[5];
    const float* b1 = (const float*)d_in[6];
    const float* W2 = (const float*)d_in[7];
    const float* b2 = (const float*)d_in[8];
    float* out = (float*)d_out;

    _Float16* R0 = (_Float16*)((char*)d_ws + R0_OFF);
    _Float16* R1 = (_Float16*)((char*)d_ws + R1_OFF);
    _Float16* Ib = (_Float16*)((char*)d_ws + I_OFF);

    // Cooperative residency: 2 blocks/CU required.
    int maxb = 0;
    hipError_t oe = hipOccupancyMaxActiveBlocksPerMultiprocessor(
        &maxb, (const void*)snn_mega_kernel, 512, 0);

    if (oe == hipSuccess && maxb >= 2) {
        void* args[] = {(void*)&x, (void*)&noise,
                        (void*)&W0, (void*)&b0, (void*)&W1, (void*)&b1,
                        (void*)&W2, (void*)&b2,
                        (void*)&R0, (void*)&R1, (void*)&Ib, (void*)&out};
        hipLaunchCooperativeKernel((const void*)snn_mega_kernel,
                                   dim3(512), dim3(512), args, 0, stream);
    } else {
        // Legacy 7-launch path (same widened bodies)
        snn_enc512_kernel<<<dim3(464), dim3(512), 0, stream>>>(x, noise, R0, out, W0, R1);
        snn_gemm64s_kernel<8, 2><<<dim3(512), dim3(512), 0, stream>>>(R1, R0, Ib);
        snn_scan_convw512_kernel<<<dim3(320), dim3(512), 0, stream>>>(Ib, b0, R1, out, 256, W1, R0);
        snn_gemm64s_kernel<8, 2><<<dim3(512), dim3(512), 0, stream>>>(R0, R1, Ib);
        snn_scan_convw512_kernel<<<dim3(272), dim3(512), 0, stream>>>(Ib, b1, R0, out, 256, W2, R1);
        snn_gemm64s_kernel<16, 4><<<dim3(512), dim3(512), 0, stream>>>(R1, R0, Ib);
        snn_scan512_kernel<<<dim3(64), dim3(512), 0, stream>>>(Ib, b2, out);
    }

    (void)in_sizes; (void)n_in; (void)out_size; (void)ws_size;
}

// Round 13
// 248.677 us; speedup vs baseline: 1.0351x; 1.0351x over previous
//
#include <hip/hip_runtime.h>
#include <hip/hip_cooperative_groups.h>

// SNN 2048->2048->2048->512, T=100, batch 32, LIF.
// R22 = RESUBMIT of R21 (round-12 bench was an infra failure -- container
// died twice, no kernel signal). R21 = EXACT R17 (proven best, 245.7us:
// mega-kernel, grid.sync boundaries, per-block scan atomic, depth-4 B
// GEMM) + ONE change:
//   scan unroll 4 -> 10. Theory: scans are HBM-latency-bound by MLP --
//   1024 waves x 4 independent I-loads x 128B = 512KB in flight / 900ns
//   = ~570 GB/s (the observed regime). I-load addresses are independent
//   of the LIF recurrence, so unroll-10 puts 2.5x more loads in flight
//   (~1.4 TB/s ceiling) without lengthening the dependent chain.
// R18 (custom gates), R19 (cons/prestage), R20 (widening) all reverted
// as measured regressions.
//
// Unified "octet-blocked" layout (pitch MTOT) for spikes AND I:
//   half_idx(v, m) = ((v>>3)*MTOT + m)*8 + (v&7)
// ws regions: R0 [0,13107200) | R1 [+13107200) | I [+26214400)
// Phases: E{enc->R0, convW0->R1} | G0 gemm(R1,R0->I) | S0{scan I->R1,
//   convW1->R0} | G1 | S1{scan I->R0, convW2->R1} | G2(256 blk) | S2->out
#define T_STEPS 100
#define MTOT    3200
#define R0_OFF  0
#define R1_OFF  13107200
#define I_OFF   26214400

typedef _Float16 half8_t __attribute__((ext_vector_type(8)));
typedef _Float16 half4_t __attribute__((ext_vector_type(4)));
typedef float    f32x4   __attribute__((ext_vector_type(4)));

// ============ encode, 512-thr, 64KB XOR-swizzled LDS ====================
__device__ __forceinline__ void encode512_body(
    int blk, const float* __restrict__ x, const float* __restrict__ noise,
    _Float16* __restrict__ spk0, float* __restrict__ out, _Float16* smem)
{
    if (blk == 0 && threadIdx.x == 0) out[16384] = 0.0f;  // runs first
    const int tid  = threadIdx.x;
    const int m0   = blk * 16;
    const int koct = tid & 255;
    const int mlh  = tid >> 8;
    half8_t* lds = (half8_t*)smem;       // [16][256]
    #pragma unroll
    for (int mlq = 0; mlq < 8; ++mlq) {
        const int ml = mlq * 2 + mlh;
        const int m  = m0 + ml;
        const int t = m >> 5, b = m & 31;
        const float4 x1 = *(const float4*)(x + b * 2048 + koct * 8);
        const float4 x2 = *(const float4*)(x + b * 2048 + koct * 8 + 4);
        const float4 n1 = *(const float4*)(noise + (size_t)t * 65536 + b * 2048 + koct * 8);
        const float4 n2 = *(const float4*)(noise + (size_t)t * 65536 + b * 2048 + koct * 8 + 4);
        const float xr[8] = {x1.x,x1.y,x1.z,x1.w,x2.x,x2.y,x2.z,x2.w};
        const float nz[8] = {n1.x,n1.y,n1.z,n1.w,n2.x,n2.y,n2.z,n2.w};
        half8_t sp;
        #pragma unroll
        for (int q = 0; q < 8; ++q) {
            const float r = fminf(fmaxf(xr[q], 0.0f), 1.0f);
            sp[q] = (nz[q] < r) ? (_Float16)1.0f : (_Float16)0.0f;
        }
        lds[ml * 256 + (koct ^ ml)] = sp;
    }
    __syncthreads();
    #pragma unroll
    for (int r = 0; r < 8; ++r) {        // lanes: ml fast -> 256B contiguous
        const int ml  = tid & 15;
        const int oct = r * 32 + (tid >> 4);
        *(half8_t*)(spk0 + ((size_t)oct * MTOT + m0 + ml) * 8)
            = lds[ml * 256 + (oct ^ ml)];
    }
    __syncthreads();                     // smem dead before phase reuse
}

// ============ convw, 512-thr: W fp32 -> fp16 A-frag swizzled ============
__device__ __forceinline__ void convw512_body(
    int cblk, const float* __restrict__ W, _Float16* __restrict__ Wf)
{
    const int koct = threadIdx.x & 255;
    const int rh   = threadIdx.x >> 8;
    #pragma unroll
    for (int r = 0; r < 8; ++r) {
        const int row = cblk * 16 + rh * 8 + r;
        const float* wp = W + (size_t)row * 2048 + koct * 8;
        const float4 f1 = *(const float4*)(wp);
        const float4 f2 = *(const float4*)(wp + 4);
        half8_t h = {(_Float16)f1.x,(_Float16)f1.y,(_Float16)f1.z,(_Float16)f1.w,
                     (_Float16)f2.x,(_Float16)f2.y,(_Float16)f2.z,(_Float16)f2.w};
        const size_t idx = (size_t)(row >> 4) * 32768
                         + ((size_t)((koct >> 2) * 64 + (koct & 3) * 16 + (row & 15))) * 8;
        *(half8_t*)(Wf + idx) = h;
    }
}

// ============ scan, 512-thr, per-BLOCK single atomic, unroll 10 =========
__device__ __forceinline__ void scan512_body(
    int blk, const _Float16* __restrict__ I, const float* __restrict__ bias,
    _Float16* __restrict__ spk_out, float* __restrict__ out,
    const int is_last, float* rsum)
{
    const int gid = blk * 512 + threadIdx.x;
    const int j   = gid & 7;
    const int b   = (gid >> 3) & 31;
    const int oct = gid >> 8;
    const int n   = oct * 8 + j;
    const float bi = bias[n];
    const size_t nbase = (size_t)oct * (MTOT * 8) + j;
    float mem = 0.f, syn = 0.f, osum = 0.f, cnt = 0.f;
    #pragma unroll 10
    for (int t = 0; t < T_STEPS; ++t) {
        const int m = t * 32 + b;
        const float Iv = (float)I[nbase + (size_t)m * 8] + bi;
        syn = syn + (-syn / 5.0f + Iv);
        mem = mem + (-mem / 20.0f + syn);
        const float sv = (mem >= 1.0f) ? 1.0f : 0.0f;
        mem = (sv != 0.0f) ? 0.0f : mem;       // reset
        mem = (mem > 0.0f) ? mem : 0.0f;       // clamp negatives
        cnt += sv; osum += sv;
        if (!is_last) spk_out[nbase + (size_t)m * 8] = (_Float16)sv;
    }
    if (is_last) out[b * 512 + n] = osum * 0.01f;    // mean over T
    // wave reduce -> LDS -> one atomic per block (G12)
    float c = cnt;
    #pragma unroll
    for (int s2 = 1; s2 < 64; s2 <<= 1) c += __shfl_xor(c, s2);
    const int wid = threadIdx.x >> 6;
    if ((threadIdx.x & 63) == 0) rsum[wid] = c;
    __syncthreads();
    if (threadIdx.x == 0) {
        float s = rsum[0];
        #pragma unroll
        for (int ww = 1; ww < 8; ++ww) s += rsum[ww];
        atomicAdd(&out[16384], s);
    }
    __syncthreads();   // rsum dead before smem reuse
}

// ============ 64-row GEMM body (R17 structure) ==========================
__device__ __forceinline__ half8_t ldB(const _Float16* __restrict__ p, int kq) {
    return *(const half8_t*)(p + (size_t)kq * (MTOT * 8));
}

__device__ __forceinline__ void stage_q(
    const _Float16* __restrict__ Wf, _Float16* __restrict__ wlds,
    const int nbb, const int q, const int w, const int lane)
{
    #pragma unroll
    for (int r = 0; r < 8; ++r) {
        const int unit = r * 512 + w * 64 + lane;        // 0..4095 (16B)
        const int s = unit >> 10, off = unit & 1023;
        const _Float16* src = Wf + (size_t)(4 * nbb + s) * 32768
                            + (size_t)q * 8192 + (size_t)off * 8;
        _Float16* dst = wlds + (size_t)unit * 8;
        __builtin_amdgcn_global_load_lds(
            (const __attribute__((address_space(1))) void*)src,
            (__attribute__((address_space(3))) void*)dst, 16, 0, 0);
    }
}

// One k-step: 4 A ds_reads feed 4|8 MFMAs; reload used B set <- kb+4.
template<bool HAS2>
__device__ __forceinline__ void kstep512(
    const _Float16* __restrict__ wlds, const _Float16* const (&bp)[2],
    half8_t (&bb)[2], f32x4 (&acc)[2][4],
    const int lane, const int quad, const int kb, const int j)
{
    half8_t a[4];
    #pragma unroll
    for (int s = 0; s < 4; ++s)
        a[s] = *(const half8_t*)(wlds + (size_t)s * 8192 + (size_t)(j * 64 + lane) * 8);
    #pragma unroll
    for (int s = 0; s < 4; ++s) {
        acc[0][s] = __builtin_amdgcn_mfma_f32_16x16x32_f16(a[s], bb[0], acc[0][s], 0, 0, 0);
        if (HAS2)
            acc[1][s] = __builtin_amdgcn_mfma_f32_16x16x32_f16(a[s], bb[1], acc[1][s], 0, 0, 0);
    }
    if (kb + 4 < 64) {                 // depth-4: reload for kb+4
        const int kq = (kb + 4) * 4 + quad;
        bb[0] = ldB(bp[0], kq);
        if (HAS2) bb[1] = ldB(bp[1], kq);
    }
}

template<bool HAS2>
__device__ __forceinline__ void gemm64s_run(
    const _Float16* __restrict__ Wf, const _Float16* __restrict__ spk,
    _Float16* __restrict__ I, _Float16* __restrict__ wlds,
    const int (&mt)[2], const int nbb, const int row_base,
    const int w, const int lane, const int quad, const int mi,
    const bool st)
{
    const _Float16* bp[2];
    bp[0] = spk + ((size_t)mt[0] * 16 + mi) * 8;
    bp[1] = spk + ((size_t)mt[1] * 16 + mi) * 8;

    // depth-4 B preload kb=0..3 FIRST (oldest in vmcnt order): the stage
    // drain at the first __syncthreads completes them for free.
    half8_t B0[2], B1[2], B2[2], B3[2];
    B0[0] = ldB(bp[0],      quad);
    B1[0] = ldB(bp[0],  4 + quad);
    B2[0] = ldB(bp[0],  8 + quad);
    B3[0] = ldB(bp[0], 12 + quad);
    if (HAS2) {
        B0[1] = ldB(bp[1],      quad);
        B1[1] = ldB(bp[1],  4 + quad);
        B2[1] = ldB(bp[1],  8 + quad);
        B3[1] = ldB(bp[1], 12 + quad);
    }

    stage_q(Wf, wlds, nbb, 0, w, lane);
    __syncthreads();

    f32x4 acc[2][4];
    #pragma unroll
    for (int u = 0; u < 2; ++u) {
        #pragma unroll
        for (int s = 0; s < 4; ++s) acc[u][s] = (f32x4){0, 0, 0, 0};
    }

    #pragma unroll 1
    for (int q = 0; q < 4; ++q) {
        #pragma unroll
        for (int j = 0; j < 16; j += 4) {
            kstep512<HAS2>(wlds, bp, B0, acc, lane, quad, q * 16 + j,     j);
            kstep512<HAS2>(wlds, bp, B1, acc, lane, quad, q * 16 + j + 1, j + 1);
            kstep512<HAS2>(wlds, bp, B2, acc, lane, quad, q * 16 + j + 2, j + 2);
            kstep512<HAS2>(wlds, bp, B3, acc, lane, quad, q * 16 + j + 3, j + 3);
        }
        __syncthreads();
        if (q < 3) {
            stage_q(Wf, wlds, nbb, q + 1, w, lane);
            __syncthreads();
        }
    }

    #pragma unroll
    for (int s = 0; s < 4; ++s) {
        const int n0 = row_base + s * 16 + quad * 4;
        const size_t obase = (size_t)(n0 >> 3) * (MTOT * 8) + (n0 & 7);
        #pragma unroll
        for (int u = 0; u < 2; ++u) {
            if (u == 0 && !st) continue;
            if (u == 1 && !HAS2) continue;
            half4_t h;
            #pragma unroll
            for (int r = 0; r < 4; ++r) h[r] = (_Float16)acc[u][s][r];
            *(half4_t*)(I + obase + (size_t)(mt[u] * 16 + mi) * 8) = h;
        }
    }
}

template<int NCHUNK>
__device__ __forceinline__ void gemm64s_body(
    const int bid, const _Float16* __restrict__ Wf,
    const _Float16* __restrict__ spk, _Float16* __restrict__ I,
    _Float16* __restrict__ wlds)
{
    const int tid  = threadIdx.x;
    const int lane = tid & 63;
    const int w    = tid >> 6;            // wave 0..7
    const int mi   = lane & 15;
    const int quad = lane >> 4;
    const int chunk = bid % NCHUNK;
    const int rest  = bid / NCHUNK;
    const int msl   = rest & 1;
    const int nbb   = rest >> 1;
    const int row_base = nbb * 64;
    const int jt     = (200 - chunk + NCHUNK - 1) / NCHUNK;
    const int jh     = (jt + 1) >> 1;
    const int jbase  = msl ? jh : 0;
    const int jcount = msl ? (jt - jh) : jh;
    const int rem    = jcount - 8;
    const bool has2  = (w < rem);
    const int r2     = rem > 0 ? rem : 0;
    const bool st    = has2 || (w + r2) < jcount;
    int jl_start = jbase + (has2 ? 2 * w : w + r2);
    const int jmax = jbase + jcount - 1;
    if (jl_start > jmax) jl_start = jmax;

    int mt[2];
    #pragma unroll
    for (int u = 0; u < 2; ++u) {
        int jl = jl_start + u;
        if (jl > jmax) jl = jmax;
        mt[u] = chunk + NCHUNK * jl;
    }

    if (has2) gemm64s_run<true >(Wf, spk, I, wlds, mt, nbb, row_base, w, lane, quad, mi, true);
    else      gemm64s_run<false>(Wf, spk, I, wlds, mt, nbb, row_base, w, lane, quad, mi, st);
}

// ==================== THE MEGA KERNEL (cooperative) =====================
__global__ __launch_bounds__(512, 4) void snn_mega_kernel(
    const float* __restrict__ x, const float* __restrict__ noise,
    const float* __restrict__ W0, const float* __restrict__ b0,
    const float* __restrict__ W1, const float* __restrict__ b1,
    const float* __restrict__ W2, const float* __restrict__ b2,
    _Float16* __restrict__ R0, _Float16* __restrict__ R1,
    _Float16* __restrict__ Ib, float* __restrict__ out)
{
    cooperative_groups::grid_group grid = cooperative_groups::this_grid();
    __shared__ _Float16 smem[32768];          // 64 KB, reused each phase
    const int blk = blockIdx.x;               // 0..511

    // E: encode -> R0 (200 blks) ; convW0 -> R1 (128 blks)
    if (blk < 200)      encode512_body(blk, x, noise, R0, out, smem);
    else if (blk < 328) convw512_body(blk - 200, W0, R1);
    grid.sync();
    // G0: gemm0(R1, R0 -> I), all 512 blocks
    gemm64s_body<8>(blk, R1, R0, Ib, smem);
    grid.sync();
    // S0: scan0 I->R1 (128 blks) ; convW1 -> R0 (128 blks)
    if (blk < 128)      scan512_body(blk, Ib, b0, R1, out, 0, (float*)smem);
    else if (blk < 256) convw512_body(blk - 128, W1, R0);
    grid.sync();
    // G1: gemm1(R0, R1 -> I)
    gemm64s_body<8>(blk, R0, R1, Ib, smem);
    grid.sync();
    // S1: scan1 I->R0 (128 blks) ; convW2 -> R1 (32 blks)
    if (blk < 128)      scan512_body(blk, Ib, b1, R0, out, 0, (float*)smem);
    else if (blk < 160) convw512_body(blk - 128, W2, R1);
    grid.sync();
    // G2: gemm2(R1, R0 -> I), 256 blocks
    if (blk < 256) gemm64s_body<16>(blk, R1, R0, Ib, smem);
    grid.sync();
    // S2: scan2 -> out (32 blks)
    if (blk < 32) scan512_body(blk, Ib, b2, nullptr, out, 1, (float*)smem);
}

// =================== legacy kernels (fallback path) =====================
__global__ __launch_bounds__(512, 4) void snn_enc512_kernel(
    const float* __restrict__ x, const float* __restrict__ noise,
    _Float16* __restrict__ spk0, float* __restrict__ out,
    const float* __restrict__ W, _Float16* __restrict__ Wf)
{
    __shared__ _Float16 smem[32768];
    if (blockIdx.x < 200) encode512_body(blockIdx.x, x, noise, spk0, out, smem);
    else                  convw512_body(blockIdx.x - 200, W, Wf);
}

__global__ __launch_bounds__(512, 4) void snn_scan_convw512_kernel(
    const _Float16* __restrict__ I, const float* __restrict__ bias,
    _Float16* __restrict__ spk_out, float* __restrict__ out,
    const int scan_blocks, const float* __restrict__ W,
    _Float16* __restrict__ Wf)
{
    __shared__ float rsum[8];
    if ((int)blockIdx.x < scan_blocks)
        scan512_body(blockIdx.x, I, bias, spk_out, out, 0, rsum);
    else
        convw512_body(blockIdx.x - scan_blocks, W, Wf);
}

__global__ __launch_bounds__(512, 4) void snn_scan512_kernel(
    const _Float16* __restrict__ I, const float* __restrict__ bias,
    float* __restrict__ out)
{
    __shared__ float rsum[8];
    scan512_body(blockIdx.x, I, bias, nullptr, out, 1, rsum);
}

template<int NCHUNK>
__global__ __launch_bounds__(512, 4) void snn_gemm64s_kernel(
    const _Float16* __restrict__ Wf, const _Float16* __restrict__ spk,
    _Float16* __restrict__ I)
{
    __shared__ _Float16 wlds[32768];
    gemm64s_body<NCHUNK>(blockIdx.x, Wf, spk, I, wlds);
}

extern "C" void kernel_launch(void* const* d_in, const int* in_sizes, int n_in,
                              void* d_out, int out_size, void* d_ws, size_t ws_size,
                              hipStream_t stream) {
    // setup_inputs() dict order: x, noise, time_steps, W0, b0, W1, b1, W2, b2
    const float* x     = (const float*)d_in[0];
    const float* noise = (const float*)d_in[1];
    const float* W0 = (const float*)d_in[3];
    const float* b0 = (const float*)d_in[4];
    const float* W1 = (const float*)d_in[5];
    const float* b1 = (const float*)d_in[6];
    const float* W2 = (const float*)d_in[7];
    const float* b2 = (const float*)d_in[8];
    float* out = (float*)d_out;

    _Float16* R0 = (_Float16*)((char*)d_ws + R0_OFF);
    _Float16* R1 = (_Float16*)((char*)d_ws + R1_OFF);
    _Float16* Ib = (_Float16*)((char*)d_ws + I_OFF);

    // Cooperative residency: 2 blocks/CU required.
    int maxb = 0;
    hipError_t oe = hipOccupancyMaxActiveBlocksPerMultiprocessor(
        &maxb, (const void*)snn_mega_kernel, 512, 0);

    if (oe == hipSuccess && maxb >= 2) {
        void* args[] = {(void*)&x, (void*)&noise,
                        (void*)&W0, (void*)&b0, (void*)&W1, (void*)&b1,
                        (void*)&W2, (void*)&b2,
                        (void*)&R0, (void*)&R1, (void*)&Ib, (void*)&out};
        hipLaunchCooperativeKernel((const void*)snn_mega_kernel,
                                   dim3(512), dim3(512), args, 0, stream);
    } else {
        // Legacy 7-launch path
        snn_enc512_kernel<<<dim3(328), dim3(512), 0, stream>>>(x, noise, R0, out, W0, R1);
        snn_gemm64s_kernel<8><<<dim3(512), dim3(512), 0, stream>>>(R1, R0, Ib);
        snn_scan_convw512_kernel<<<dim3(256), dim3(512), 0, stream>>>(Ib, b0, R1, out, 128, W1, R0);
        snn_gemm64s_kernel<8><<<dim3(512), dim3(512), 0, stream>>>(R0, R1, Ib);
        snn_scan_convw512_kernel<<<dim3(160), dim3(512), 0, stream>>>(Ib, b1, R0, out, 128, W2, R1);
        snn_gemm64s_kernel<16><<<dim3(256), dim3(512), 0, stream>>>(R1, R0, Ib);
        snn_scan512_kernel<<<dim3(32), dim3(512), 0, stream>>>(Ib, b2, out);
    }

    (void)in_sizes; (void)n_in; (void)out_size; (void)ws_size;
}

// Round 14
// 247.216 us; speedup vs baseline: 1.0413x; 1.0059x over previous
//
#include <hip/hip_runtime.h>
#include <hip/hip_cooperative_groups.h>

// SNN 2048->2048->2048->512, T=100, batch 32, LIF.
// R23 = FINAL: exact restore of R17, the best-measured configuration
// (245.7 us). Session findings baked in:
//   - cooperative mega-kernel, 512 blk x 512 thr x 64KB LDS (2 blocks/CU),
//     6 grid.sync boundaries (== 7-launch cost, R15/R16; custom striped
//     gates are WORSE, R18).
//   - 64-row GEMM tile, 4 A-subtiles/block: each B-load feeds 4 MFMAs
//     (B-L2 halved -- R11's win); 2 independent blocks/CU (R14's win).
//   - scan: per-BLOCK single atomic (R17's win, -28us: same-address
//     device-scope atomics serialize at ~12ns each); coalesced remap
//     (R15); unroll 4 (unroll 10 = no effect, R21).
//   - REFUTED by measurement (do not retry): staging-drain pipelining
//     (R12), K-split wave pairs (R13), E-phase consolidation + A-prestage
//     (R19), phase widening (R20), B keep-alive pinning + setprio (R18).
// Structural constraint: 7 phases are irreducibly serial (every GEMM
// consumes the full predecessor output across k; every scan needs all T).
// All pipes <35%; each phase is latency-bound at the parallelism the
// problem admits. This is the design's floor, not a HW roofline.
//
// Unified "octet-blocked" layout (pitch MTOT) for spikes AND I:
//   half_idx(v, m) = ((v>>3)*MTOT + m)*8 + (v&7)
// ws regions: R0 [0,13107200) | R1 [+13107200) | I [+26214400)
// Phases: E{enc->R0, convW0->R1} | G0 gemm(R1,R0->I) | S0{scan I->R1,
//   convW1->R0} | G1 | S1{scan I->R0, convW2->R1} | G2(256 blk) | S2->out
#define T_STEPS 100
#define MTOT    3200
#define R0_OFF  0
#define R1_OFF  13107200
#define I_OFF   26214400

typedef _Float16 half8_t __attribute__((ext_vector_type(8)));
typedef _Float16 half4_t __attribute__((ext_vector_type(4)));
typedef float    f32x4   __attribute__((ext_vector_type(4)));

// ============ encode, 512-thr, 64KB XOR-swizzled LDS ====================
__device__ __forceinline__ void encode512_body(
    int blk, const float* __restrict__ x, const float* __restrict__ noise,
    _Float16* __restrict__ spk0, float* __restrict__ out, _Float16* smem)
{
    if (blk == 0 && threadIdx.x == 0) out[16384] = 0.0f;  // runs first
    const int tid  = threadIdx.x;
    const int m0   = blk * 16;
    const int koct = tid & 255;
    const int mlh  = tid >> 8;
    half8_t* lds = (half8_t*)smem;       // [16][256]
    #pragma unroll
    for (int mlq = 0; mlq < 8; ++mlq) {
        const int ml = mlq * 2 + mlh;
        const int m  = m0 + ml;
        const int t = m >> 5, b = m & 31;
        const float4 x1 = *(const float4*)(x + b * 2048 + koct * 8);
        const float4 x2 = *(const float4*)(x + b * 2048 + koct * 8 + 4);
        const float4 n1 = *(const float4*)(noise + (size_t)t * 65536 + b * 2048 + koct * 8);
        const float4 n2 = *(const float4*)(noise + (size_t)t * 65536 + b * 2048 + koct * 8 + 4);
        const float xr[8] = {x1.x,x1.y,x1.z,x1.w,x2.x,x2.y,x2.z,x2.w};
        const float nz[8] = {n1.x,n1.y,n1.z,n1.w,n2.x,n2.y,n2.z,n2.w};
        half8_t sp;
        #pragma unroll
        for (int q = 0; q < 8; ++q) {
            const float r = fminf(fmaxf(xr[q], 0.0f), 1.0f);
            sp[q] = (nz[q] < r) ? (_Float16)1.0f : (_Float16)0.0f;
        }
        lds[ml * 256 + (koct ^ ml)] = sp;
    }
    __syncthreads();
    #pragma unroll
    for (int r = 0; r < 8; ++r) {        // lanes: ml fast -> 256B contiguous
        const int ml  = tid & 15;
        const int oct = r * 32 + (tid >> 4);
        *(half8_t*)(spk0 + ((size_t)oct * MTOT + m0 + ml) * 8)
            = lds[ml * 256 + (oct ^ ml)];
    }
    __syncthreads();                     // smem dead before phase reuse
}

// ============ convw, 512-thr: W fp32 -> fp16 A-frag swizzled ============
__device__ __forceinline__ void convw512_body(
    int cblk, const float* __restrict__ W, _Float16* __restrict__ Wf)
{
    const int koct = threadIdx.x & 255;
    const int rh   = threadIdx.x >> 8;
    #pragma unroll
    for (int r = 0; r < 8; ++r) {
        const int row = cblk * 16 + rh * 8 + r;
        const float* wp = W + (size_t)row * 2048 + koct * 8;
        const float4 f1 = *(const float4*)(wp);
        const float4 f2 = *(const float4*)(wp + 4);
        half8_t h = {(_Float16)f1.x,(_Float16)f1.y,(_Float16)f1.z,(_Float16)f1.w,
                     (_Float16)f2.x,(_Float16)f2.y,(_Float16)f2.z,(_Float16)f2.w};
        const size_t idx = (size_t)(row >> 4) * 32768
                         + ((size_t)((koct >> 2) * 64 + (koct & 3) * 16 + (row & 15))) * 8;
        *(half8_t*)(Wf + idx) = h;
    }
}

// ============ scan, 512-thr, per-BLOCK single atomic ====================
// R15 coalesced remap: j=gid&7, b=(gid>>3)&31, oct=gid>>8 -> a wave's
// per-t loads/stores are 128B contiguous.
__device__ __forceinline__ void scan512_body(
    int blk, const _Float16* __restrict__ I, const float* __restrict__ bias,
    _Float16* __restrict__ spk_out, float* __restrict__ out,
    const int is_last, float* rsum)
{
    const int gid = blk * 512 + threadIdx.x;
    const int j   = gid & 7;
    const int b   = (gid >> 3) & 31;
    const int oct = gid >> 8;
    const int n   = oct * 8 + j;
    const float bi = bias[n];
    const size_t nbase = (size_t)oct * (MTOT * 8) + j;
    float mem = 0.f, syn = 0.f, osum = 0.f, cnt = 0.f;
    #pragma unroll 4
    for (int t = 0; t < T_STEPS; ++t) {
        const int m = t * 32 + b;
        const float Iv = (float)I[nbase + (size_t)m * 8] + bi;
        syn = syn + (-syn / 5.0f + Iv);
        mem = mem + (-mem / 20.0f + syn);
        const float sv = (mem >= 1.0f) ? 1.0f : 0.0f;
        mem = (sv != 0.0f) ? 0.0f : mem;       // reset
        mem = (mem > 0.0f) ? mem : 0.0f;       // clamp negatives
        cnt += sv; osum += sv;
        if (!is_last) spk_out[nbase + (size_t)m * 8] = (_Float16)sv;
    }
    if (is_last) out[b * 512 + n] = osum * 0.01f;    // mean over T
    // wave reduce -> LDS -> one atomic per block (G12; R17's win)
    float c = cnt;
    #pragma unroll
    for (int s2 = 1; s2 < 64; s2 <<= 1) c += __shfl_xor(c, s2);
    const int wid = threadIdx.x >> 6;
    if ((threadIdx.x & 63) == 0) rsum[wid] = c;
    __syncthreads();
    if (threadIdx.x == 0) {
        float s = rsum[0];
        #pragma unroll
        for (int ww = 1; ww < 8; ++ww) s += rsum[ww];
        atomicAdd(&out[16384], s);
    }
    __syncthreads();   // rsum dead before smem reuse
}

// ============ 64-row GEMM body (R14/R17 structure) ======================
__device__ __forceinline__ half8_t ldB(const _Float16* __restrict__ p, int kq) {
    return *(const half8_t*)(p + (size_t)kq * (MTOT * 8));
}

__device__ __forceinline__ void stage_q(
    const _Float16* __restrict__ Wf, _Float16* __restrict__ wlds,
    const int nbb, const int q, const int w, const int lane)
{
    #pragma unroll
    for (int r = 0; r < 8; ++r) {
        const int unit = r * 512 + w * 64 + lane;        // 0..4095 (16B)
        const int s = unit >> 10, off = unit & 1023;
        const _Float16* src = Wf + (size_t)(4 * nbb + s) * 32768
                            + (size_t)q * 8192 + (size_t)off * 8;
        _Float16* dst = wlds + (size_t)unit * 8;
        __builtin_amdgcn_global_load_lds(
            (const __attribute__((address_space(1))) void*)src,
            (__attribute__((address_space(3))) void*)dst, 16, 0, 0);
    }
}

// One k-step: 4 A ds_reads feed 4|8 MFMAs; reload used B set <- kb+4.
template<bool HAS2>
__device__ __forceinline__ void kstep512(
    const _Float16* __restrict__ wlds, const _Float16* const (&bp)[2],
    half8_t (&bb)[2], f32x4 (&acc)[2][4],
    const int lane, const int quad, const int kb, const int j)
{
    half8_t a[4];
    #pragma unroll
    for (int s = 0; s < 4; ++s)
        a[s] = *(const half8_t*)(wlds + (size_t)s * 8192 + (size_t)(j * 64 + lane) * 8);
    #pragma unroll
    for (int s = 0; s < 4; ++s) {
        acc[0][s] = __builtin_amdgcn_mfma_f32_16x16x32_f16(a[s], bb[0], acc[0][s], 0, 0, 0);
        if (HAS2)
            acc[1][s] = __builtin_amdgcn_mfma_f32_16x16x32_f16(a[s], bb[1], acc[1][s], 0, 0, 0);
    }
    if (kb + 4 < 64) {                 // depth-4: reload for kb+4
        const int kq = (kb + 4) * 4 + quad;
        bb[0] = ldB(bp[0], kq);
        if (HAS2) bb[1] = ldB(bp[1], kq);
    }
}

template<bool HAS2>
__device__ __forceinline__ void gemm64s_run(
    const _Float16* __restrict__ Wf, const _Float16* __restrict__ spk,
    _Float16* __restrict__ I, _Float16* __restrict__ wlds,
    const int (&mt)[2], const int nbb, const int row_base,
    const int w, const int lane, const int quad, const int mi,
    const bool st)
{
    const _Float16* bp[2];
    bp[0] = spk + ((size_t)mt[0] * 16 + mi) * 8;
    bp[1] = spk + ((size_t)mt[1] * 16 + mi) * 8;

    // depth-4 B preload kb=0..3 FIRST (oldest in vmcnt order): the stage
    // drain at the first __syncthreads completes them for free.
    half8_t B0[2], B1[2], B2[2], B3[2];
    B0[0] = ldB(bp[0],      quad);
    B1[0] = ldB(bp[0],  4 + quad);
    B2[0] = ldB(bp[0],  8 + quad);
    B3[0] = ldB(bp[0], 12 + quad);
    if (HAS2) {
        B0[1] = ldB(bp[1],      quad);
        B1[1] = ldB(bp[1],  4 + quad);
        B2[1] = ldB(bp[1],  8 + quad);
        B3[1] = ldB(bp[1], 12 + quad);
    }

    stage_q(Wf, wlds, nbb, 0, w, lane);
    __syncthreads();

    f32x4 acc[2][4];
    #pragma unroll
    for (int u = 0; u < 2; ++u) {
        #pragma unroll
        for (int s = 0; s < 4; ++s) acc[u][s] = (f32x4){0, 0, 0, 0};
    }

    #pragma unroll 1
    for (int q = 0; q < 4; ++q) {
        #pragma unroll
        for (int j = 0; j < 16; j += 4) {
            kstep512<HAS2>(wlds, bp, B0, acc, lane, quad, q * 16 + j,     j);
            kstep512<HAS2>(wlds, bp, B1, acc, lane, quad, q * 16 + j + 1, j + 1);
            kstep512<HAS2>(wlds, bp, B2, acc, lane, quad, q * 16 + j + 2, j + 2);
            kstep512<HAS2>(wlds, bp, B3, acc, lane, quad, q * 16 + j + 3, j + 3);
        }
        __syncthreads();
        if (q < 3) {
            stage_q(Wf, wlds, nbb, q + 1, w, lane);
            __syncthreads();
        }
    }

    #pragma unroll
    for (int s = 0; s < 4; ++s) {
        const int n0 = row_base + s * 16 + quad * 4;
        const size_t obase = (size_t)(n0 >> 3) * (MTOT * 8) + (n0 & 7);
        #pragma unroll
        for (int u = 0; u < 2; ++u) {
            if (u == 0 && !st) continue;
            if (u == 1 && !HAS2) continue;
            half4_t h;
            #pragma unroll
            for (int r = 0; r < 4; ++r) h[r] = (_Float16)acc[u][s][r];
            *(half4_t*)(I + obase + (size_t)(mt[u] * 16 + mi) * 8) = h;
        }
    }
}

template<int NCHUNK>
__device__ __forceinline__ void gemm64s_body(
    const int bid, const _Float16* __restrict__ Wf,
    const _Float16* __restrict__ spk, _Float16* __restrict__ I,
    _Float16* __restrict__ wlds)
{
    const int tid  = threadIdx.x;
    const int lane = tid & 63;
    const int w    = tid >> 6;            // wave 0..7
    const int mi   = lane & 15;
    const int quad = lane >> 4;
    const int chunk = bid % NCHUNK;
    const int rest  = bid / NCHUNK;
    const int msl   = rest & 1;
    const int nbb   = rest >> 1;
    const int row_base = nbb * 64;
    const int jt     = (200 - chunk + NCHUNK - 1) / NCHUNK;
    const int jh     = (jt + 1) >> 1;
    const int jbase  = msl ? jh : 0;
    const int jcount = msl ? (jt - jh) : jh;
    const int rem    = jcount - 8;
    const bool has2  = (w < rem);
    const int r2     = rem > 0 ? rem : 0;
    const bool st    = has2 || (w + r2) < jcount;
    int jl_start = jbase + (has2 ? 2 * w : w + r2);
    const int jmax = jbase + jcount - 1;
    if (jl_start > jmax) jl_start = jmax;

    int mt[2];
    #pragma unroll
    for (int u = 0; u < 2; ++u) {
        int jl = jl_start + u;
        if (jl > jmax) jl = jmax;
        mt[u] = chunk + NCHUNK * jl;
    }

    if (has2) gemm64s_run<true >(Wf, spk, I, wlds, mt, nbb, row_base, w, lane, quad, mi, true);
    else      gemm64s_run<false>(Wf, spk, I, wlds, mt, nbb, row_base, w, lane, quad, mi, st);
}

// ==================== THE MEGA KERNEL (cooperative) =====================
__global__ __launch_bounds__(512, 4) void snn_mega_kernel(
    const float* __restrict__ x, const float* __restrict__ noise,
    const float* __restrict__ W0, const float* __restrict__ b0,
    const float* __restrict__ W1, const float* __restrict__ b1,
    const float* __restrict__ W2, const float* __restrict__ b2,
    _Float16* __restrict__ R0, _Float16* __restrict__ R1,
    _Float16* __restrict__ Ib, float* __restrict__ out)
{
    cooperative_groups::grid_group grid = cooperative_groups::this_grid();
    __shared__ _Float16 smem[32768];          // 64 KB, reused each phase
    const int blk = blockIdx.x;               // 0..511

    // E: encode -> R0 (200 blks) ; convW0 -> R1 (128 blks)
    if (blk < 200)      encode512_body(blk, x, noise, R0, out, smem);
    else if (blk < 328) convw512_body(blk - 200, W0, R1);
    grid.sync();
    // G0: gemm0(R1, R0 -> I), all 512 blocks
    gemm64s_body<8>(blk, R1, R0, Ib, smem);
    grid.sync();
    // S0: scan0 I->R1 (128 blks) ; convW1 -> R0 (128 blks)
    if (blk < 128)      scan512_body(blk, Ib, b0, R1, out, 0, (float*)smem);
    else if (blk < 256) convw512_body(blk - 128, W1, R0);
    grid.sync();
    // G1: gemm1(R0, R1 -> I)
    gemm64s_body<8>(blk, R0, R1, Ib, smem);
    grid.sync();
    // S1: scan1 I->R0 (128 blks) ; convW2 -> R1 (32 blks)
    if (blk < 128)      scan512_body(blk, Ib, b1, R0, out, 0, (float*)smem);
    else if (blk < 160) convw512_body(blk - 128, W2, R1);
    grid.sync();
    // G2: gemm2(R1, R0 -> I), 256 blocks
    if (blk < 256) gemm64s_body<16>(blk, R1, R0, Ib, smem);
    grid.sync();
    // S2: scan2 -> out (32 blks)
    if (blk < 32) scan512_body(blk, Ib, b2, nullptr, out, 1, (float*)smem);
}

// =================== legacy kernels (fallback path) =====================
__global__ __launch_bounds__(512, 4) void snn_enc512_kernel(
    const float* __restrict__ x, const float* __restrict__ noise,
    _Float16* __restrict__ spk0, float* __restrict__ out,
    const float* __restrict__ W, _Float16* __restrict__ Wf)
{
    __shared__ _Float16 smem[32768];
    if (blockIdx.x < 200) encode512_body(blockIdx.x, x, noise, spk0, out, smem);
    else                  convw512_body(blockIdx.x - 200, W, Wf);
}

__global__ __launch_bounds__(512, 4) void snn_scan_convw512_kernel(
    const _Float16* __restrict__ I, const float* __restrict__ bias,
    _Float16* __restrict__ spk_out, float* __restrict__ out,
    const int scan_blocks, const float* __restrict__ W,
    _Float16* __restrict__ Wf)
{
    __shared__ float rsum[8];
    if ((int)blockIdx.x < scan_blocks)
        scan512_body(blockIdx.x, I, bias, spk_out, out, 0, rsum);
    else
        convw512_body(blockIdx.x - scan_blocks, W, Wf);
}

__global__ __launch_bounds__(512, 4) void snn_scan512_kernel(
    const _Float16* __restrict__ I, const float* __restrict__ bias,
    float* __restrict__ out)
{
    __shared__ float rsum[8];
    scan512_body(blockIdx.x, I, bias, nullptr, out, 1, rsum);
}

template<int NCHUNK>
__global__ __launch_bounds__(512, 4) void snn_gemm64s_kernel(
    const _Float16* __restrict__ Wf, const _Float16* __restrict__ spk,
    _Float16* __restrict__ I)
{
    __shared__ _Float16 wlds[32768];
    gemm64s_body<NCHUNK>(blockIdx.x, Wf, spk, I, wlds);
}

extern "C" void kernel_launch(void* const* d_in, const int* in_sizes, int n_in,
                              void* d_out, int out_size, void* d_ws, size_t ws_size,
                              hipStream_t stream) {
    // setup_inputs() dict order: x, noise, time_steps, W0, b0, W1, b1, W2, b2
    const float* x     = (const float*)d_in[0];
    const float* noise = (const float*)d_in[1];
    const float* W0 = (const float*)d_in[3];
    const float* b0 = (const float*)d_in[4];
    const float* W1 = (const float*)d_in[5];
    const float* b1 = (const float*)d_in[6];
    const float* W2 = (const float*)d_in[7];
    const float* b2 = (const float*)d_in[8];
    float* out = (float*)d_out;

    _Float16* R0 = (_Float16*)((char*)d_ws + R0_OFF);
    _Float16* R1 = (_Float16*)((char*)d_ws + R1_OFF);
    _Float16* Ib = (_Float16*)((char*)d_ws + I_OFF);

    // Cooperative residency: 2 blocks/CU required.
    int maxb = 0;
    hipError_t oe = hipOccupancyMaxActiveBlocksPerMultiprocessor(
        &maxb, (const void*)snn_mega_kernel, 512, 0);

    if (oe == hipSuccess && maxb >= 2) {
        void* args[] = {(void*)&x, (void*)&noise,
                        (void*)&W0, (void*)&b0, (void*)&W1, (void*)&b1,
                        (void*)&W2, (void*)&b2,
                        (void*)&R0, (void*)&R1, (void*)&Ib, (void*)&out};
        hipLaunchCooperativeKernel((const void*)snn_mega_kernel,
                                   dim3(512), dim3(512), args, 0, stream);
    } else {
        // Legacy 7-launch path
        snn_enc512_kernel<<<dim3(328), dim3(512), 0, stream>>>(x, noise, R0, out, W0, R1);
        snn_gemm64s_kernel<8><<<dim3(512), dim3(512), 0, stream>>>(R1, R0, Ib);
        snn_scan_convw512_kernel<<<dim3(256), dim3(512), 0, stream>>>(Ib, b0, R1, out, 128, W1, R0);
        snn_gemm64s_kernel<8><<<dim3(512), dim3(512), 0, stream>>>(R0, R1, Ib);
        snn_scan_convw512_kernel<<<dim3(160), dim3(512), 0, stream>>>(Ib, b1, R0, out, 128, W2, R1);
        snn_gemm64s_kernel<16><<<dim3(256), dim3(512), 0, stream>>>(R1, R0, Ib);
        snn_scan512_kernel<<<dim3(32), dim3(512), 0, stream>>>(Ib, b2, out);
    }

    (void)in_sizes; (void)n_in; (void)out_size; (void)ws_size;
}